// Round 10
// baseline (3214.535 us; speedup 1.0000x reference)
//
#include <hip/hip_runtime.h>
#include <hip/hip_bf16.h>

// alphaLSTMNetwork: B=2048 sequential steps, E=16 elevators.
//   G1: pg0  = feat @ pre_Wih0^T + bih0 + bhh0            [B*16, 256]  (parallel)
//   G2: pgo  = feat @ out_Wih[:,64:]^T + bih + bhh        [B*16, 512]  (parallel)
//   K2: per-elevator 2-layer pre-LSTM + fc recurrence     (16 blocks, seq over t)
//   G4: gih  = x @ comm_Wih0^T + bih0 + bhh0              [B*16, 128]  (parallel)
//   K3: comm alpha-LSTM, 48 micro-steps, state resets/t   (1 wave per t, parallel)
//   G6: gg   = group @ out_Wih[:,:64]^T                   [B, 512]     (parallel)
//   K4: per-elevator out-LSTM recurrence                  (16 blocks, seq over t)
//   K5: heads (tar/dir softmax)                           (parallel)
// R10 = R9 (2999us: DPP quad gate-gather) + ONE change: batched x4 global
// prefetch in k2/k4. Every step used to issue a load that the same step's
// __syncthreads vmcnt(0)-drain waited on (~300-500cy L3). Now 4 steps of
// loads issue once per group into named ping-pong banks (used 4-7 steps
// later): 3 of 4 barriers have zero outstanding vmem -> drain free; the
// group-top drain overlaps the step's own compute.

#define E_ 16
#define F_ 128

typedef int i4 __attribute__((ext_vector_type(4)));
typedef _Float16 hf;
typedef hf hf2 __attribute__((ext_vector_type(2)));

__device__ __forceinline__ float sigf(float x) { return 1.0f / (1.0f + __expf(-x)); }
__device__ __forceinline__ float tanhf_(float x) {
  float e = __expf(2.0f * x);
  return 1.0f - 2.0f / (e + 1.0f);
}
__device__ __forceinline__ float lane_bcast(float v, int k) {
  return __int_as_float(__builtin_amdgcn_readlane(__float_as_int(v), k));
}
__device__ __forceinline__ float fdot2(int a, int b, float c) {
#if __has_builtin(__builtin_amdgcn_fdot2)
  return __builtin_amdgcn_fdot2(__builtin_bit_cast(hf2, a),
                                __builtin_bit_cast(hf2, b), c, false);
#else
  float d;
  asm("v_dot2_f32_f16 %0, %1, %2, %3" : "=v"(d) : "v"(a), "v"(b), "v"(c));
  return d;
#endif
}

// Canonical DPP quad_perm butterflies (full-rate VALU, no LDS pipe).
// 0xB1 = quad_perm(1,0,3,2) -> lane^1 ; 0x4E = quad_perm(2,3,0,1) -> lane^2.
__device__ __forceinline__ float dpp_xor1(float x) {
  return __int_as_float(__builtin_amdgcn_update_dpp(
      __float_as_int(x), __float_as_int(x), 0xB1, 0xF, 0xF, true));
}
__device__ __forceinline__ float dpp_xor2(float x) {
  return __int_as_float(__builtin_amdgcn_update_dpp(
      __float_as_int(x), __float_as_int(x), 0x4E, 0xF, 0xF, true));
}

// ---------------------------------------------------------------------------
// fp32 -> fp16 weight conversion (one-time per call, tiny)
// ---------------------------------------------------------------------------
__global__ void f2h_kernel(const float* __restrict__ src, hf* __restrict__ dst, int n) {
  int i = blockIdx.x * 256 + threadIdx.x;
  if (i < n) dst[i] = (hf)src[i];
}

// ---------------------------------------------------------------------------
// Generic skinny GEMM: C[m,n] = sum_k A[m,k]*W[n, co+k] (+b1[n]+b2[n])
// ---------------------------------------------------------------------------
__global__ __launch_bounds__(256) void gemm_k(
    const float* __restrict__ A, int lda,
    const float* __restrict__ W, int ldw, int co,
    const float* __restrict__ b1, const float* __restrict__ b2,
    float* __restrict__ C, int N, int K) {
  __shared__ float As[64 * 65];
  __shared__ float Ws[128 * 65];
  const int tid = threadIdx.x;
  const int m0 = blockIdx.x * 64;
  const int n0 = blockIdx.y * 128;
  const int rr = tid >> 4;
  const int c4 = (tid & 15) << 2;
  const int tm = tid >> 4;
  const int tn = tid & 15;

  float acc[4][8];
#pragma unroll
  for (int i = 0; i < 4; ++i)
#pragma unroll
    for (int j = 0; j < 8; ++j) acc[i][j] = 0.0f;

  for (int kk = 0; kk < K; kk += 64) {
#pragma unroll
    for (int p = 0; p < 4; ++p) {
      const int r = rr + p * 16;
      const float4 v = *(const float4*)(A + (size_t)(m0 + r) * lda + kk + c4);
      float* dst = &As[r * 65 + c4];
      dst[0] = v.x; dst[1] = v.y; dst[2] = v.z; dst[3] = v.w;
    }
#pragma unroll
    for (int p = 0; p < 8; ++p) {
      const int n = rr + p * 16;
      const float4 v = *(const float4*)(W + (size_t)(n0 + n) * ldw + co + kk + c4);
      float* dst = &Ws[n * 65 + c4];
      dst[0] = v.x; dst[1] = v.y; dst[2] = v.z; dst[3] = v.w;
    }
    __syncthreads();
#pragma unroll 4
    for (int k = 0; k < 64; ++k) {
      float a[4], wv[8];
#pragma unroll
      for (int i = 0; i < 4; ++i) a[i] = As[(tm * 4 + i) * 65 + k];
#pragma unroll
      for (int j = 0; j < 8; ++j) wv[j] = Ws[(tn * 8 + j) * 65 + k];
#pragma unroll
      for (int i = 0; i < 4; ++i)
#pragma unroll
        for (int j = 0; j < 8; ++j) acc[i][j] += a[i] * wv[j];
    }
    __syncthreads();
  }
#pragma unroll
  for (int i = 0; i < 4; ++i) {
    const int m = m0 + tm * 4 + i;
#pragma unroll
    for (int j = 0; j < 8; ++j) {
      const int n = n0 + tn * 8 + j;
      float v = acc[i][j];
      if (b1) v += b1[n];
      if (b2) v += b2[n];
      C[(size_t)m * N + n] = v;
    }
  }
}

// ---------------------------------------------------------------------------
// K2: per-elevator pre-LSTM (2 layers) + fc. 16 blocks x 576 threads (9 waves).
// Waves 0-3 (A): L0 step n.  Waves 4-7 (B): L1 step n-1.  Wave 8 (C): fc step n-2.
// QUAD layout: lane cls = l&3 owns gate cls (i,f,g,o) of elem j = wg*16+(l>>2);
// gate gather via DPP quad_perm xor2 then xor1; f-lane (cls1) owns c.
// ONE __syncthreads per step; batched x4 pg0 prefetch (ping-pong banks).
// ---------------------------------------------------------------------------
__global__ __launch_bounds__(576) void k2_pre(
    const float* __restrict__ pg0, const float* __restrict__ preh,
    const float* __restrict__ prec,
    const hf* __restrict__ hWhh0, const hf* __restrict__ hWih1,
    const hf* __restrict__ hWhh1, const hf* __restrict__ hfcW,
    const float* __restrict__ bih1, const float* __restrict__ bhh1,
    const float* __restrict__ fcb, float* __restrict__ xout, int B) {
  const int e = blockIdx.x, tid = threadIdx.x;
  const int wv = tid >> 6, l = tid & 63;
  const int cls = l & 3;              // gate class within the quad: i,f,g,o
  __shared__ __align__(16) hf h0s[2][64];
  __shared__ __align__(16) hf h1s[2][64];

  int wa[32], wb[32];
  float bias = 0.f, c = 0.f;
  const float* pgp = nullptr;
  int j = 0;

  if (wv < 4) {                       // group A: L0
    j = wv * 16 + (l >> 2);
    const int r = cls * 64 + j;
    const i4* p0 = (const i4*)(hWhh0 + r * 64);
#pragma unroll
    for (int i = 0; i < 8; ++i) {
      i4 a = p0[i]; wa[4*i]=a.x; wa[4*i+1]=a.y; wa[4*i+2]=a.z; wa[4*i+3]=a.w;
    }
    pgp = pg0 + (size_t)e * 256 + r;
    if (cls == 1) { c = prec[e * 128 + j]; h0s[1][j] = (hf)preh[e * 128 + j]; }
  } else if (wv < 8) {                // group B: L1
    j = (wv - 4) * 16 + (l >> 2);
    const int r = cls * 64 + j;
    const i4* p1 = (const i4*)(hWih1 + r * 64);
    const i4* p2 = (const i4*)(hWhh1 + r * 64);
#pragma unroll
    for (int i = 0; i < 8; ++i) {
      i4 a = p1[i]; wa[4*i]=a.x; wa[4*i+1]=a.y; wa[4*i+2]=a.z; wa[4*i+3]=a.w;
      i4 b = p2[i]; wb[4*i]=b.x; wb[4*i+1]=b.y; wb[4*i+2]=b.z; wb[4*i+3]=b.w;
    }
    bias = bih1[cls * 64 + j] + bhh1[cls * 64 + j];
    if (cls == 1) { c = prec[e * 128 + 64 + j]; h1s[1][j] = (hf)preh[e * 128 + 64 + j]; }
  } else {                            // group C: fc
    j = l;
    const i4* pf = (const i4*)(hfcW + l * 64);
#pragma unroll
    for (int i = 0; i < 8; ++i) {
      i4 a = pf[i]; wa[4*i]=a.x; wa[4*i+1]=a.y; wa[4*i+2]=a.z; wa[4*i+3]=a.w;
    }
    bias = fcb[l];
  }
  __syncthreads();

  auto doL0 = [&](int nn, float pgv) {
    const i4* hp = (const i4*)h0s[(nn + 1) & 1];          // h0(nn-1)
    float a0 = 0.f, a1 = 0.f, a2 = 0.f, a3 = 0.f;
#pragma unroll
    for (int i = 0; i < 8; ++i) {
      i4 h = hp[i];
      a0 = fdot2(wa[4*i],   h.x, a0); a1 = fdot2(wa[4*i+1], h.y, a1);
      a2 = fdot2(wa[4*i+2], h.z, a2); a3 = fdot2(wa[4*i+3], h.w, a3);
    }
    const float pre = (a0 + a1) + (a2 + a3) + pgv;        // pg0 has x-part+biases
    const float act = (cls == 2) ? tanhf_(pre) : sigf(pre);
    const float p2 = dpp_xor2(act);                       // cls0<-tanh(g), cls1<-sig(o)
    const float ig = act * p2;                            // cls0: sig(i)*tanh(g)
    const float p1 = dpp_xor1(ig);                        // cls1<-ig
    if (cls == 1) {
      c = act * c + p1;                                   // act = sig(f)
      h0s[nn & 1][j] = (hf)(p2 * tanhf_(c));              // p2 = sig(o)
    }
  };
  auto doL1 = [&](int nn) {
    const i4* hp0 = (const i4*)h0s[(nn + 1) & 1];         // h0(nn-1)
    const i4* hp1 = (const i4*)h1s[nn & 1];               // h1(nn-2)
    float a0 = 0.f, a1 = 0.f, a2 = 0.f, a3 = 0.f;
#pragma unroll
    for (int i = 0; i < 8; ++i) {
      i4 h = hp0[i];
      a0 = fdot2(wa[4*i],   h.x, a0); a1 = fdot2(wa[4*i+1], h.y, a1);
      a2 = fdot2(wa[4*i+2], h.z, a2); a3 = fdot2(wa[4*i+3], h.w, a3);
    }
#pragma unroll
    for (int i = 0; i < 8; ++i) {
      i4 h = hp1[i];
      a0 = fdot2(wb[4*i],   h.x, a0); a1 = fdot2(wb[4*i+1], h.y, a1);
      a2 = fdot2(wb[4*i+2], h.z, a2); a3 = fdot2(wb[4*i+3], h.w, a3);
    }
    const float pre = (a0 + a1) + (a2 + a3) + bias;
    const float act = (cls == 2) ? tanhf_(pre) : sigf(pre);
    const float p2 = dpp_xor2(act);
    const float ig = act * p2;
    const float p1 = dpp_xor1(ig);
    if (cls == 1) {
      c = act * c + p1;
      h1s[(nn + 1) & 1][j] = (hf)(p2 * tanhf_(c));        // h1(nn-1) -> buf (nn-1)&1
    }
  };
  auto doFC = [&](int nn) {
    const i4* hp1 = (const i4*)h1s[nn & 1];               // h1(nn-2)
    float a0 = 0.f, a1 = 0.f, a2 = 0.f, a3 = 0.f;
#pragma unroll
    for (int i = 0; i < 8; ++i) {
      i4 h = hp1[i];
      a0 = fdot2(wa[4*i],   h.x, a0); a1 = fdot2(wa[4*i+1], h.y, a1);
      a2 = fdot2(wa[4*i+2], h.z, a2); a3 = fdot2(wa[4*i+3], h.w, a3);
    }
    const float xv = (a0 + a1) + (a2 + a3) + bias;
    xout[((size_t)(nn - 2) * E_ + e) * 64 + l] = (xv > 0.f) ? xv : 0.05f * xv;
  };

  // batched x4 prefetch, ping-pong named banks (used 4-7 steps after issue)
  auto ld = [&](int k) -> float {
    return (k < B) ? pgp[(size_t)k * 4096] : 0.f;
  };
  float pA0 = 0.f, pA1 = 0.f, pA2 = 0.f, pA3 = 0.f;
  float pB0 = 0.f, pB1 = 0.f, pB2 = 0.f, pB3 = 0.f;
  if (wv < 4) { pA0 = ld(0); pA1 = ld(1); pA2 = ld(2); pA3 = ld(3); }

#define K2STEP(NN, PR)                                     \
  {                                                        \
    const int nn = (NN);                                   \
    if (wv < 4) { if (nn < B) doL0(nn, PR); }              \
    else if (wv < 8) { if (nn >= 1 && nn <= B) doL1(nn); } \
    else { if (nn >= 2 && nn < B + 2) doFC(nn); }          \
    __syncthreads();                                       \
  }

  const int NT8 = (B + 2 + 7) & ~7;
  for (int n = 0; n < NT8; n += 8) {
    if (wv < 4) { pB0 = ld(n + 4); pB1 = ld(n + 5); pB2 = ld(n + 6); pB3 = ld(n + 7); }
    K2STEP(n + 0, pA0) K2STEP(n + 1, pA1) K2STEP(n + 2, pA2) K2STEP(n + 3, pA3)
    if (wv < 4) { pA0 = ld(n + 8); pA1 = ld(n + 9); pA2 = ld(n + 10); pA3 = ld(n + 11); }
    K2STEP(n + 4, pB0) K2STEP(n + 5, pB1) K2STEP(n + 6, pB2) K2STEP(n + 7, pB3)
  }
#undef K2STEP
}

// ---------------------------------------------------------------------------
// K3: communication alpha-LSTM. One wave per timestep t (state resets each t).
// ---------------------------------------------------------------------------
__global__ __launch_bounds__(256) void k3_comm(
    const float* __restrict__ gih0, const float* __restrict__ Whh0,
    const float* __restrict__ Wih1, const float* __restrict__ Whh1,
    const float* __restrict__ bih1, const float* __restrict__ bhh1,
    float* __restrict__ grp, int B) {
  const int w = threadIdx.x >> 6;
  const int l = threadIdx.x & 63;
  const int t = blockIdx.x * 4 + w;

  float wh0a[32], wh0b[32], wi1a[32], wi1b[32], wh1a[32], wh1b[32];
#pragma unroll
  for (int i = 0; i < 32; ++i) {
    wh0a[i] = Whh0[l * 32 + i];         wh0b[i] = Whh0[(l + 64) * 32 + i];
    wi1a[i] = Wih1[l * 32 + i];         wi1b[i] = Wih1[(l + 64) * 32 + i];
    wh1a[i] = Whh1[l * 32 + i];         wh1b[i] = Whh1[(l + 64) * 32 + i];
  }
  const float cb1a = bih1[l] + bhh1[l];
  const float cb1b = bih1[l + 64] + bhh1[l + 64];

  float h0 = 0.0f, c0 = 0.0f, h1 = 0.0f, c1 = 0.0f;
  float al = 1.0f;
  const float* gbase = gih0 + (size_t)t * (E_ * 128);
  for (int r = 0; r < 3; ++r) {
    for (int e = 0; e < E_; ++e) {
      float ga = gbase[e * 128 + l];
      float gb = gbase[e * 128 + l + 64];
#pragma unroll
      for (int k = 0; k < 32; ++k) {
        const float hv = lane_bcast(h0, k);
        ga += wh0a[k] * hv;
        gb += wh0b[k] * hv;
      }
      {
        const float fa = __shfl_xor(ga, 32);
        const float ob = __shfl_xor(gb, 32);
        c0 = sigf(fa) * c0 + al * sigf(ga) * tanhf_(gb);
        h0 = sigf(ob) * tanhf_(c0);
      }
      float ga1 = cb1a, gb1 = cb1b;
#pragma unroll
      for (int k = 0; k < 32; ++k) {
        const float hv = lane_bcast(h0, k);
        ga1 += wi1a[k] * hv;
        gb1 += wi1b[k] * hv;
      }
#pragma unroll
      for (int k = 0; k < 32; ++k) {
        const float hv = lane_bcast(h1, k);
        ga1 += wh1a[k] * hv;
        gb1 += wh1b[k] * hv;
      }
      {
        const float fa = __shfl_xor(ga1, 32);
        const float ob = __shfl_xor(gb1, 32);
        c1 = sigf(fa) * c1 + al * sigf(ga1) * tanhf_(gb1);
        h1 = sigf(ob) * tanhf_(c1);
      }
    }
    al *= 0.333f;
  }
  if (l < 32) {
    grp[(size_t)t * 64 + l] = c0;
    grp[(size_t)t * 64 + 32 + l] = c1;
  }
}

// ---------------------------------------------------------------------------
// K4: per-elevator out-LSTM. 16 blocks x 512 threads (8 waves).
// QUAD layout: elem j = wave*16+(l>>2), gate cls=l&3, row r=cls*128+j;
// 64 dot2/thread. Gate gather via DPP xor2/xor1; f-lane owns c;
// ONE barrier/step. Batched x4 pgo/gg prefetch (ping-pong banks).
// ---------------------------------------------------------------------------
__global__ __launch_bounds__(512) void k4_out(
    const float* __restrict__ pgo, const float* __restrict__ gg,
    const float* __restrict__ outh, const float* __restrict__ outc,
    const hf* __restrict__ hWo, float* __restrict__ noh, int B) {
  const int e = blockIdx.x, tid = threadIdx.x;
  const int wv = tid >> 6, l = tid & 63;
  const int cls = l & 3;
  const int j = wv * 16 + (l >> 2);
  const int r = cls * 128 + j;
  __shared__ __align__(16) hf hs[2][128];

  int w[64];
  {
    const i4* pw = (const i4*)(hWo + (size_t)r * 128);
#pragma unroll
    for (int i = 0; i < 16; ++i) {
      i4 a = pw[i]; w[4*i]=a.x; w[4*i+1]=a.y; w[4*i+2]=a.z; w[4*i+3]=a.w;
    }
  }
  float c = 0.f;
  if (cls == 1) { c = outc[e * 128 + j]; hs[1][j] = (hf)outh[e * 128 + j]; }
  __syncthreads();

  const float* pgoP = pgo + (size_t)e * 512 + r;   // + tt*8192
  const float* ggP  = gg + r;                      // + tt*512

  auto doStep = [&](int nn, float po, float gv) {
    const i4* hp = (const i4*)hs[(nn + 1) & 1];       // h(nn-1)
    float a0 = 0.f, a1 = 0.f, a2 = 0.f, a3 = 0.f;
#pragma unroll
    for (int i = 0; i < 16; ++i) {
      i4 h = hp[i];
      a0 = fdot2(w[4*i],   h.x, a0); a1 = fdot2(w[4*i+1], h.y, a1);
      a2 = fdot2(w[4*i+2], h.z, a2); a3 = fdot2(w[4*i+3], h.w, a3);
    }
    const float pre = (a0 + a1) + (a2 + a3) + po + gv;   // pgo has biases
    const float act = (cls == 2) ? tanhf_(pre) : sigf(pre);
    const float p2 = dpp_xor2(act);                      // cls0<-tanh(g), cls1<-sig(o)
    const float ig = act * p2;
    const float p1 = dpp_xor1(ig);                       // cls1<-ig
    if (cls == 1) {
      c = act * c + p1;
      const float h = p2 * tanhf_(c);
      hs[nn & 1][j] = (hf)h;
      noh[((size_t)nn * E_ + e) * 128 + j] = h;
    }
  };

  auto ldp = [&](int k) -> float {
    return (k < B) ? pgoP[(size_t)k * 8192] : 0.f;
  };
  auto ldg = [&](int k) -> float {
    return (k < B) ? ggP[(size_t)k * 512] : 0.f;
  };
  float oA0 = ldp(0), oA1 = ldp(1), oA2 = ldp(2), oA3 = ldp(3);
  float gA0 = ldg(0), gA1 = ldg(1), gA2 = ldg(2), gA3 = ldg(3);
  float oB0 = 0.f, oB1 = 0.f, oB2 = 0.f, oB3 = 0.f;
  float gB0 = 0.f, gB1 = 0.f, gB2 = 0.f, gB3 = 0.f;

#define K4STEP(NN, PO, GV)                                 \
  {                                                        \
    const int nn = (NN);                                   \
    if (nn < B) doStep(nn, PO, GV);                        \
    __syncthreads();                                       \
  }

  const int NT8 = (B + 7) & ~7;
  for (int n = 0; n < NT8; n += 8) {
    oB0 = ldp(n + 4); oB1 = ldp(n + 5); oB2 = ldp(n + 6); oB3 = ldp(n + 7);
    gB0 = ldg(n + 4); gB1 = ldg(n + 5); gB2 = ldg(n + 6); gB3 = ldg(n + 7);
    K4STEP(n + 0, oA0, gA0) K4STEP(n + 1, oA1, gA1)
    K4STEP(n + 2, oA2, gA2) K4STEP(n + 3, oA3, gA3)
    oA0 = ldp(n + 8); oA1 = ldp(n + 9); oA2 = ldp(n + 10); oA3 = ldp(n + 11);
    gA0 = ldg(n + 8); gA1 = ldg(n + 9); gA2 = ldg(n + 10); gA3 = ldg(n + 11);
    K4STEP(n + 4, oB0, gB0) K4STEP(n + 5, oB1, gB1)
    K4STEP(n + 6, oB2, gB2) K4STEP(n + 7, oB3, gB3)
  }
#undef K4STEP
}

// ---------------------------------------------------------------------------
// K5: heads. tar = softmax(noh@tarW^T + tb) [64], dir = softmax(noh@dirW^T + db) [3].
// ---------------------------------------------------------------------------
__global__ __launch_bounds__(256) void k5_heads(
    const float* __restrict__ noh, const float* __restrict__ tarW,
    const float* __restrict__ tarb, const float* __restrict__ dirW,
    const float* __restrict__ dirb, float* __restrict__ out) {
  __shared__ float tw[128 * 64];
  __shared__ float tb[64];
  const int tid = threadIdx.x;
  for (int idx = tid; idx < 8192; idx += 256) {
    const int j = idx >> 7, k = idx & 127;
    tw[k * 64 + j] = tarW[idx];
  }
  if (tid < 64) tb[tid] = tarb[tid];
  __syncthreads();
  const int w = tid >> 6, l = tid & 63;
  const float db0 = dirb[0], db1 = dirb[1], db2 = dirb[2];

  for (int p = 0; p < 16; ++p) {
    const int row = blockIdx.x * 64 + p * 4 + w;
    const float na = noh[(size_t)row * 128 + l];
    const float nb = noh[(size_t)row * 128 + 64 + l];
    float acc = tb[l];
#pragma unroll
    for (int k = 0; k < 64; ++k) acc += tw[k * 64 + l] * lane_bcast(na, k);
#pragma unroll
    for (int k = 0; k < 64; ++k) acc += tw[(64 + k) * 64 + l] * lane_bcast(nb, k);
    float m = acc;
#pragma unroll
    for (int s = 32; s; s >>= 1) m = fmaxf(m, __shfl_xor(m, s));
    const float ex = __expf(acc - m);
    float sm = ex;
#pragma unroll
    for (int s = 32; s; s >>= 1) sm += __shfl_xor(sm, s);
    out[(size_t)row * 67 + l] = ex / sm;
    float d0 = dirW[l] * na + dirW[64 + l] * nb;
    float d1 = dirW[128 + l] * na + dirW[192 + l] * nb;
    float d2 = dirW[256 + l] * na + dirW[320 + l] * nb;
#pragma unroll
    for (int s = 32; s; s >>= 1) {
      d0 += __shfl_xor(d0, s);
      d1 += __shfl_xor(d1, s);
      d2 += __shfl_xor(d2, s);
    }
    d0 += db0; d1 += db1; d2 += db2;
    const float dm = fmaxf(d0, fmaxf(d1, d2));
    const float e0 = __expf(d0 - dm), e1 = __expf(d1 - dm), e2 = __expf(d2 - dm);
    const float ds = e0 + e1 + e2;
    if (l < 3) out[(size_t)row * 67 + 64 + l] = (l == 0 ? e0 : (l == 1 ? e1 : e2)) / ds;
  }
}

// ---------------------------------------------------------------------------
extern "C" void kernel_launch(void* const* d_in, const int* in_sizes, int n_in,
                              void* d_out, int out_size, void* d_ws, size_t ws_size,
                              hipStream_t stream) {
  const float* features = (const float*)d_in[0];
  const float* pre_h    = (const float*)d_in[1];
  const float* pre_c    = (const float*)d_in[2];
  const float* out_h    = (const float*)d_in[3];
  const float* out_c    = (const float*)d_in[4];
  const float* pre_Wih0 = (const float*)d_in[5];
  const float* pre_Whh0 = (const float*)d_in[6];
  const float* pre_bih0 = (const float*)d_in[7];
  const float* pre_bhh0 = (const float*)d_in[8];
  const float* pre_Wih1 = (const float*)d_in[9];
  const float* pre_Whh1 = (const float*)d_in[10];
  const float* pre_bih1 = (const float*)d_in[11];
  const float* pre_bhh1 = (const float*)d_in[12];
  const float* fc_W     = (const float*)d_in[13];
  const float* fc_b     = (const float*)d_in[14];
  const float* comm_Wih0 = (const float*)d_in[15];
  const float* comm_Whh0 = (const float*)d_in[16];
  const float* comm_bih0 = (const float*)d_in[17];
  const float* comm_bhh0 = (const float*)d_in[18];
  const float* comm_Wih1 = (const float*)d_in[19];
  const float* comm_Whh1 = (const float*)d_in[20];
  const float* comm_bih1 = (const float*)d_in[21];
  const float* comm_bhh1 = (const float*)d_in[22];
  const float* out_Wih  = (const float*)d_in[23];
  const float* out_Whh  = (const float*)d_in[24];
  const float* out_bih  = (const float*)d_in[25];
  const float* out_bhh  = (const float*)d_in[26];
  const float* tar_W    = (const float*)d_in[27];
  const float* tar_b    = (const float*)d_in[28];
  const float* dir_W    = (const float*)d_in[29];
  const float* dir_b    = (const float*)d_in[30];

  const int B = in_sizes[0] / (E_ * F_);   // 2048
  float* ws = (float*)d_ws;
  float* pg0 = ws;                                  // [B*16, 256]
  float* pgo = pg0 + (size_t)B * E_ * 256;          // [B*16, 512]
  float* xbf = pgo + (size_t)B * E_ * 512;          // [B*16, 64]
  float* gih = xbf + (size_t)B * E_ * 64;           // [B*16, 128]
  float* grp = gih + (size_t)B * E_ * 128;          // [B, 64]
  float* gg  = grp + (size_t)B * 64;                // [B, 512]
  float* noh = gg + (size_t)B * 512;                // [B*16, 128]
  hf* hWhh0 = (hf*)(noh + (size_t)B * E_ * 128);    // [256*64]
  hf* hWih1 = hWhh0 + 256 * 64;                     // [256*64]
  hf* hWhh1 = hWih1 + 256 * 64;                     // [256*64]
  hf* hfcW  = hWhh1 + 256 * 64;                     // [64*64]
  hf* hWo   = hfcW + 64 * 64;                       // [512*128]
  (void)ws_size; (void)n_in; (void)out_size;

  // W0: fp32 -> fp16 weight packs for the recurrence kernels
  f2h_kernel<<<(256 * 64 + 255) / 256, 256, 0, stream>>>(pre_Whh0, hWhh0, 256 * 64);
  f2h_kernel<<<(256 * 64 + 255) / 256, 256, 0, stream>>>(pre_Wih1, hWih1, 256 * 64);
  f2h_kernel<<<(256 * 64 + 255) / 256, 256, 0, stream>>>(pre_Whh1, hWhh1, 256 * 64);
  f2h_kernel<<<(64 * 64 + 255) / 256, 256, 0, stream>>>(fc_W, hfcW, 64 * 64);
  f2h_kernel<<<(512 * 128 + 255) / 256, 256, 0, stream>>>(out_Whh, hWo, 512 * 128);

  const int MB = B * E_ / 64;

  // G1: pre-LSTM layer0 input projection (+ both biases)
  gemm_k<<<dim3(MB, 2), 256, 0, stream>>>(features, 128, pre_Wih0, 128, 0,
                                          pre_bih0, pre_bhh0, pg0, 256, 128);
  // G2: out-LSTM feat-half input projection (+ both biases)
  gemm_k<<<dim3(MB, 4), 256, 0, stream>>>(features, 128, out_Wih, 192, 64,
                                          out_bih, out_bhh, pgo, 512, 128);
  // K2: pre recurrence (writes x)
  k2_pre<<<E_, 576, 0, stream>>>(pg0, pre_h, pre_c, hWhh0, hWih1, hWhh1, hfcW,
                                 pre_bih1, pre_bhh1, fc_b, xbf, B);
  // G4: comm layer0 input projection (+ both biases)
  gemm_k<<<dim3(MB, 1), 256, 0, stream>>>(xbf, 64, comm_Wih0, 64, 0,
                                          comm_bih0, comm_bhh0, gih, 128, 64);
  // K3: comm chains (writes group cell states)
  k3_comm<<<B / 4, 256, 0, stream>>>(gih, comm_Whh0, comm_Wih1, comm_Whh1,
                                     comm_bih1, comm_bhh1, grp, B);
  // G6: out-LSTM group-half input projection
  gemm_k<<<dim3(B / 64, 4), 256, 0, stream>>>(grp, 64, out_Wih, 192, 0,
                                              nullptr, nullptr, gg, 512, 64);
  // K4: out recurrence (writes noh)
  k4_out<<<E_, 512, 0, stream>>>(pgo, gg, out_h, out_c, hWo, noh, B);
  // K5: heads + softmax -> d_out [B,16,67]
  k5_heads<<<B * E_ / 64, 256, 0, stream>>>(noh, tar_W, tar_b, dir_W, dir_b,
                                            (float*)d_out);
}